// Round 1
// baseline (87.708 us; speedup 1.0000x reference)
//
#include <hip/hip_runtime.h>
#include <hip/hip_bf16.h>

// Problem constants (fixed by the reference)
#define NUM_WORDS 200000
#define EMBED 128
#define BATCH 16384
#define WIN 8

typedef __attribute__((ext_vector_type(8))) short short8;   // 8 bf16 in 4 VGPRs
typedef __attribute__((ext_vector_type(4))) float f32x4;

__device__ __forceinline__ short f2bf(float f) {
  unsigned u = __float_as_uint(f);
  u = u + 0x7FFFu + ((u >> 16) & 1u);   // round-to-nearest-even
  return (short)(u >> 16);
}

__device__ __forceinline__ float sp(float x) {   // stable softplus
  return fmaxf(x, 0.f) + __logf(1.f + __expf(-fabsf(x)));
}
__device__ __forceinline__ float logmix(float w) {
  float a = w * w;
  // log(0.5*exp(-w^2/2) + 0.5*exp(-w^2/(2*0.2^2)))
  return __logf(0.5f * __expf(-0.5f * a) + 0.5f * __expf(-12.5f * a));
}
__device__ __forceinline__ float ftanh(float x) {
  x = fminf(fmaxf(x, -15.f), 15.f);
  float e = __expf(2.f * x);
  return (e - 1.f) / (e + 1.f);
}

// ---------------------------------------------------------------------------
// Pre-pass: pack B-fragments of A^T = lin_w[:, :128]^T (bf16, MFMA B layout)
// and cov_proj[c][j] = lin_b[j] + sum_k cov_w[c][k]*lin_w[j][128+k]  (f32)
// ---------------------------------------------------------------------------
__global__ void prep_kernel(const float* __restrict__ lin_w,
                            const float* __restrict__ lin_b,
                            const float* __restrict__ cov_w,
                            short* __restrict__ bpack,
                            float* __restrict__ covp) {
  int t = blockIdx.x * 256 + threadIdx.x;
  if (t < 16384) {
    // t = ((wv*4+kk)*2+jt)*512 + l*8 + e
    int e  = t & 7;
    int l  = (t >> 3) & 63;
    int jt = (t >> 9) & 1;
    int kk = (t >> 10) & 3;
    int wv = (t >> 12) & 3;
    int j = wv * 32 + jt * 16 + (l & 15);        // B col (N)
    int k = kk * 32 + (l >> 4) * 8 + e;          // B row (K)
    bpack[t] = f2bf(lin_w[j * 256 + k]);         // B[k][n] = lin_w[j][k]
  } else if (t < 16384 + 1280) {
    int u = t - 16384;
    int c = u >> 7, j = u & 127;
    float s = lin_b[j];
    for (int k = 0; k < 128; ++k)
      s += cov_w[c * 128 + k] * lin_w[j * 256 + 128 + k];
    covp[u] = s;
  }
}

// ---------------------------------------------------------------------------
// Main kernel: one block = 16 b's. Phase 1: MFMA matvec + per-b terms.
// Phase 2: per-(b,w) gathered rows, dots, priors. Deterministic reduction.
// ---------------------------------------------------------------------------
__global__ __launch_bounds__(256) void main_kernel(
    const int* __restrict__ inputs, const int* __restrict__ outputs,
    const int* __restrict__ covars, const int* __restrict__ noise,
    const float* __restrict__ wtp,
    const float* __restrict__ eps_in, const float* __restrict__ eps_out,
    const float* __restrict__ in_w, const float* __restrict__ out_w,
    const float* __restrict__ in_rho_w, const float* __restrict__ out_rho_w,
    const short* __restrict__ bpack, const float* __restrict__ covp,
    double* __restrict__ parts) {
  __shared__ float w_s[16][132];   // w_pre transpose buffer (padded)
  __shared__ float red_s[4];

  const int tid  = threadIdx.x;
  const int lane = tid & 63;
  const int wv   = tid >> 6;       // wave id (owns j slice [32*wv, 32*wv+32))
  const int q    = lane >> 4;
  const int f16  = lane & 15;
  const int bbase = blockIdx.x * 16;
  const float wtv = wtp[0];

  // -------- load resident B fragments (bf16 A^T slice for this wave) --------
  short8 bfrag[4][2];
  const int4* bp = (const int4*)bpack;
  #pragma unroll
  for (int kk = 0; kk < 4; ++kk) {
    #pragma unroll
    for (int jt = 0; jt < 2; ++jt) {
      int fi = (wv * 4 + kk) * 2 + jt;
      int4 v = bp[fi * 64 + lane];
      bfrag[kk][jt] = __builtin_bit_cast(short8, v);
    }
  }

  // -------- phase 1: MFMA matvec  w_pre = mu_in @ lin_w[:, :128]^T ----------
  // A layout: lane supplies row b = lane&15, k = kk*32 + (lane>>4)*8 + e
  int idxA = inputs[bbase + f16];
  f32x4 acc0 = {0.f, 0.f, 0.f, 0.f}, acc1 = {0.f, 0.f, 0.f, 0.f};
  #pragma unroll
  for (int kk = 0; kk < 4; ++kk) {
    const float* ap = in_w + (size_t)idxA * 128 + kk * 32 + q * 8;
    float4 a0 = *(const float4*)ap;
    float4 a1 = *(const float4*)(ap + 4);
    short8 af;
    af[0] = f2bf(a0.x); af[1] = f2bf(a0.y); af[2] = f2bf(a0.z); af[3] = f2bf(a0.w);
    af[4] = f2bf(a1.x); af[5] = f2bf(a1.y); af[6] = f2bf(a1.z); af[7] = f2bf(a1.w);
    acc0 = __builtin_amdgcn_mfma_f32_16x16x32_bf16(af, bfrag[kk][0], acc0, 0, 0, 0);
    acc1 = __builtin_amdgcn_mfma_f32_16x16x32_bf16(af, bfrag[kk][1], acc1, 0, 0, 0);
  }
  // D layout: lane holds D[b = q*4+r][j = wv*32 + jt*16 + f16]
  #pragma unroll
  for (int r = 0; r < 4; ++r) {
    w_s[q * 4 + r][wv * 32 + f16]      = acc0[r];
    w_s[q * 4 + r][wv * 32 + 16 + f16] = acc1[r];
  }
  __syncthreads();

  // -------- phase 1 row pass: quarter-wave (tid>>4) owns b = tid>>4 ---------
  const int b  = tid >> 4;
  const int f  = tid & 15;           // lane-in-quarter, owns j = f*8 .. f*8+7
  const int gb = bbase + b;
  const int idx = inputs[gb];
  const int cov = covars[gb];

  float wp[8];
  *(float4*)(wp)     = *(const float4*)(&w_s[b][f * 8]);
  *(float4*)(wp + 4) = *(const float4*)(&w_s[b][f * 8 + 4]);
  float4 rh0 = *(const float4*)(in_rho_w + (size_t)idx * 128 + f * 8);
  float4 rh1 = *(const float4*)(in_rho_w + (size_t)idx * 128 + f * 8 + 4);
  float4 ep0 = *(const float4*)(eps_in + (size_t)gb * 128 + f * 8);
  float4 ep1 = *(const float4*)(eps_in + (size_t)gb * 128 + f * 8 + 4);
  float4 cv0 = *(const float4*)(covp + cov * 128 + f * 8);
  float4 cv1 = *(const float4*)(covp + cov * 128 + f * 8 + 4);
  float rh[8] = {rh0.x, rh0.y, rh0.z, rh0.w, rh1.x, rh1.y, rh1.z, rh1.w};
  float ep[8] = {ep0.x, ep0.y, ep0.z, ep0.w, ep1.x, ep1.y, ep1.z, ep1.w};
  float cv[8] = {cv0.x, cv0.y, cv0.z, cv0.w, cv1.x, cv1.y, cv1.z, cv1.w};

  float wi[8];
  float t1 = 0.f, pr = 0.f;
  #pragma unroll
  for (int e = 0; e < 8; ++e) {
    float s = sp(rh[e]);                       // sigma_in
    float w = ftanh(wp[e] + cv[e]) + s * ep[e];
    wi[e] = w;                                 // w_in kept in registers
    t1 += -0.5f * ep[e] * ep[e] - __logf(s);   // post_in part
    pr += logmix(w);                           // prior_in part
  }
  float red = t1 - pr;
  #pragma unroll
  for (int m = 1; m <= 8; m <<= 1) red += __shfl_xor(red, m, 64);
  float accum = (f == 0) ? 8.f * wtv * red : 0.f;

  // -------- phase 2: 8 rows (b, w) per quarter-wave -------------------------
  #pragma unroll 2
  for (int w = 0; w < 8; ++w) {
    const int r  = gb * 8 + w;
    const int o  = outputs[r];
    const int nz = noise[r];
    const float* wrow = out_w     + (size_t)o  * 128 + f * 8;
    const float* rrow = out_rho_w + (size_t)o  * 128 + f * 8;
    const float* erow = eps_out   + (size_t)r  * 128 + f * 8;
    const float* nrow = out_w     + (size_t)nz * 128 + f * 8;
    float4 mo0 = *(const float4*)wrow,       mo1 = *(const float4*)(wrow + 4);
    float4 ro0 = *(const float4*)rrow,       ro1 = *(const float4*)(rrow + 4);
    float4 eo0 = *(const float4*)erow,       eo1 = *(const float4*)(erow + 4);
    float4 nv0 = *(const float4*)nrow,       nv1 = *(const float4*)(nrow + 4);
    float mo[8] = {mo0.x, mo0.y, mo0.z, mo0.w, mo1.x, mo1.y, mo1.z, mo1.w};
    float ro[8] = {ro0.x, ro0.y, ro0.z, ro0.w, ro1.x, ro1.y, ro1.z, ro1.w};
    float eo[8] = {eo0.x, eo0.y, eo0.z, eo0.w, eo1.x, eo1.y, eo1.z, eo1.w};
    float nv[8] = {nv0.x, nv0.y, nv0.z, nv0.w, nv1.x, nv1.y, nv1.z, nv1.w};

    float t2 = 0.f, d1 = 0.f, d2 = 0.f;
    #pragma unroll
    for (int e = 0; e < 8; ++e) {
      float s  = sp(ro[e]);
      float wo = mo[e] + s * eo[e];
      t2 += -0.5f * eo[e] * eo[e] - __logf(s) - logmix(wo);  // post_out - prior_out
      d1 += wi[e] * wo;
      d2 -= wi[e] * nv[e];
    }
    #pragma unroll
    for (int m = 1; m <= 8; m <<= 1) {
      t2 += __shfl_xor(t2, m, 64);
      d1 += __shfl_xor(d1, m, 64);
      d2 += __shfl_xor(d2, m, 64);
    }
    float term = wtv * t2 + sp(-d1) + sp(-d2);   // -likelihood = sp(-d1)+sp(-d2)
    accum += (f == 0) ? term : 0.f;
  }

  // -------- deterministic block reduction ----------------------------------
  #pragma unroll
  for (int m = 1; m <= 32; m <<= 1) accum += __shfl_xor(accum, m, 64);
  if (lane == 0) red_s[wv] = accum;
  __syncthreads();
  if (tid == 0) {
    double s = (double)red_s[0] + (double)red_s[1] + (double)red_s[2] + (double)red_s[3];
    parts[blockIdx.x] = s;
  }
}

// ---------------------------------------------------------------------------
// Final deterministic reduction: 1024 block partials -> mean
// ---------------------------------------------------------------------------
__global__ void fin_kernel(const double* __restrict__ parts, float* __restrict__ out) {
  __shared__ double s[256];
  const int tid = threadIdx.x;
  double a = 0.0;
  for (int i = tid; i < 1024; i += 256) a += parts[i];
  s[tid] = a;
  __syncthreads();
  for (int st = 128; st > 0; st >>= 1) {
    if (tid < st) s[tid] += s[tid + st];
    __syncthreads();
  }
  if (tid == 0) out[0] = (float)(s[0] / (double)(BATCH * WIN));
}

extern "C" void kernel_launch(void* const* d_in, const int* in_sizes, int n_in,
                              void* d_out, int out_size, void* d_ws, size_t ws_size,
                              hipStream_t stream) {
  const int*   inputs    = (const int*)d_in[0];
  const int*   outputs   = (const int*)d_in[1];
  const int*   covars    = (const int*)d_in[2];
  const int*   noise     = (const int*)d_in[3];
  const float* wt        = (const float*)d_in[4];
  const float* eps_in    = (const float*)d_in[5];
  const float* eps_out   = (const float*)d_in[6];
  const float* in_w      = (const float*)d_in[7];
  const float* out_w     = (const float*)d_in[8];
  const float* in_rho_w  = (const float*)d_in[9];
  const float* out_rho_w = (const float*)d_in[10];
  const float* cov_w     = (const float*)d_in[11];
  const float* lin_w     = (const float*)d_in[12];
  const float* lin_b     = (const float*)d_in[13];

  short*  bpack = (short*)d_ws;                            // 32768 B
  float*  covp  = (float*)((char*)d_ws + 32768);           // 5120 B
  double* parts = (double*)((char*)d_ws + 40960);          // 8192 B

  prep_kernel<<<69, 256, 0, stream>>>(lin_w, lin_b, cov_w, bpack, covp);
  main_kernel<<<1024, 256, 0, stream>>>(inputs, outputs, covars, noise, wt,
                                        eps_in, eps_out, in_w, out_w,
                                        in_rho_w, out_rho_w, bpack, covp, parts);
  fin_kernel<<<1, 256, 0, stream>>>(parts, (float*)d_out);
}

// Round 2
// 68.968 us; speedup vs baseline: 1.2717x; 1.2717x over previous
//
#include <hip/hip_runtime.h>
#include <hip/hip_bf16.h>

// Problem constants (fixed by the reference)
#define NUM_WORDS 200000
#define EMBED 128
#define BATCH 16384
#define WIN 8
#define B_PER_BLK 8
#define GRID (BATCH / B_PER_BLK)   // 2048 blocks -> 8 blocks/CU -> 100% occupancy

typedef __attribute__((ext_vector_type(8))) short short8;   // 8 bf16 in 4 VGPRs
typedef __attribute__((ext_vector_type(4))) float f32x4;

__device__ __forceinline__ short f2bf(float f) {
  unsigned u = __float_as_uint(f);
  u = u + 0x7FFFu + ((u >> 16) & 1u);   // round-to-nearest-even
  return (short)(u >> 16);
}

__device__ __forceinline__ float sp(float x) {   // stable softplus
  return fmaxf(x, 0.f) + __logf(1.f + __expf(-fabsf(x)));
}
__device__ __forceinline__ float logmix(float w) {
  float a = w * w;
  // log(0.5*exp(-w^2/2) + 0.5*exp(-w^2/(2*0.2^2)))
  return __logf(0.5f * __expf(-0.5f * a) + 0.5f * __expf(-12.5f * a));
}
__device__ __forceinline__ float ftanh(float x) {
  x = fminf(fmaxf(x, -15.f), 15.f);
  float e = __expf(2.f * x);
  return (e - 1.f) / (e + 1.f);
}

// ---------------------------------------------------------------------------
// Pre-pass: pack B-fragments of A^T = lin_w[:, :128]^T (bf16, MFMA B layout)
// and cov_proj[c][j] = lin_b[j] + sum_k cov_w[c][k]*lin_w[j][128+k]  (f32)
// ---------------------------------------------------------------------------
__global__ void prep_kernel(const float* __restrict__ lin_w,
                            const float* __restrict__ lin_b,
                            const float* __restrict__ cov_w,
                            short* __restrict__ bpack,
                            float* __restrict__ covp) {
  int t = blockIdx.x * 256 + threadIdx.x;
  if (t < 16384) {
    // t = ((wv*4+kk)*2+jt)*512 + l*8 + e
    int e  = t & 7;
    int l  = (t >> 3) & 63;
    int jt = (t >> 9) & 1;
    int kk = (t >> 10) & 3;
    int wv = (t >> 12) & 3;
    int j = wv * 32 + jt * 16 + (l & 15);        // B col (N)
    int k = kk * 32 + (l >> 4) * 8 + e;          // B row (K)
    bpack[t] = f2bf(lin_w[j * 256 + k]);         // B[k][n] = lin_w[j][k]
  } else if (t < 16384 + 1280) {
    int u = t - 16384;
    int c = u >> 7, j = u & 127;
    float s = lin_b[j];
    for (int k = 0; k < 128; ++k)
      s += cov_w[c * 128 + k] * lin_w[j * 256 + 128 + k];
    covp[u] = s;
  }
}

// ---------------------------------------------------------------------------
// Main kernel: one block = 8 b's (grid 2048 -> full occupancy).
// Phase 1: MFMA matvec (rows 8..15 are clamped duplicates) + per-b terms.
// Phase 2: two quarter-waves per b, 4 windows each. Deterministic reduction.
// ---------------------------------------------------------------------------
__global__ __launch_bounds__(256, 8) void main_kernel(
    const int* __restrict__ inputs, const int* __restrict__ outputs,
    const int* __restrict__ covars, const int* __restrict__ noise,
    const float* __restrict__ wtp,
    const float* __restrict__ eps_in, const float* __restrict__ eps_out,
    const float* __restrict__ in_w, const float* __restrict__ out_w,
    const float* __restrict__ in_rho_w, const float* __restrict__ out_rho_w,
    const short* __restrict__ bpack, const float* __restrict__ covp,
    double* __restrict__ parts) {
  __shared__ float w_s[B_PER_BLK][132];   // w_pre, then w_in (padded stride)
  __shared__ float red_s[4];

  const int tid  = threadIdx.x;
  const int lane = tid & 63;
  const int wv   = tid >> 6;       // wave id (owns j slice [32*wv, 32*wv+32))
  const int q    = lane >> 4;
  const int f16  = lane & 15;
  const int bbase = blockIdx.x * B_PER_BLK;
  const float wtv = wtp[0];

  // -------- load resident B fragments (bf16 A^T slice for this wave) --------
  short8 bfrag[4][2];
  const int4* bp = (const int4*)bpack;
  #pragma unroll
  for (int kk = 0; kk < 4; ++kk) {
    #pragma unroll
    for (int jt = 0; jt < 2; ++jt) {
      int fi = (wv * 4 + kk) * 2 + jt;
      int4 v = bp[fi * 64 + lane];
      bfrag[kk][jt] = __builtin_bit_cast(short8, v);
    }
  }

  // -------- phase 1: MFMA matvec  w_pre = mu_in @ lin_w[:, :128]^T ----------
  // A layout: lane supplies row b = lane&15 (clamped to 8 valid), k = kk*32+q*8+e
  int idxA = inputs[bbase + (f16 & (B_PER_BLK - 1))];
  f32x4 acc0 = {0.f, 0.f, 0.f, 0.f}, acc1 = {0.f, 0.f, 0.f, 0.f};
  #pragma unroll
  for (int kk = 0; kk < 4; ++kk) {
    const float* ap = in_w + (size_t)idxA * 128 + kk * 32 + q * 8;
    float4 a0 = *(const float4*)ap;
    float4 a1 = *(const float4*)(ap + 4);
    short8 af;
    af[0] = f2bf(a0.x); af[1] = f2bf(a0.y); af[2] = f2bf(a0.z); af[3] = f2bf(a0.w);
    af[4] = f2bf(a1.x); af[5] = f2bf(a1.y); af[6] = f2bf(a1.z); af[7] = f2bf(a1.w);
    acc0 = __builtin_amdgcn_mfma_f32_16x16x32_bf16(af, bfrag[kk][0], acc0, 0, 0, 0);
    acc1 = __builtin_amdgcn_mfma_f32_16x16x32_bf16(af, bfrag[kk][1], acc1, 0, 0, 0);
  }
  // D layout: lane holds D[b = q*4+r][j = wv*32 + jt*16 + f16]; keep rows < 8
  #pragma unroll
  for (int r = 0; r < 4; ++r) {
    int row = q * 4 + r;
    if (row < B_PER_BLK) {
      w_s[row][wv * 32 + f16]      = acc0[r];
      w_s[row][wv * 32 + 16 + f16] = acc1[r];
    }
  }
  __syncthreads();

  // -------- phase 1 row pass: tid<128, (b = tid>>4, f = tid&15) -------------
  const int f = tid & 15;            // lane-in-quarter, owns j = f*8 .. f*8+7
  float accum = 0.f;
  if (tid < B_PER_BLK * 16) {
    const int b  = tid >> 4;
    const int gb = bbase + b;
    const int idx = inputs[gb];
    const int cov = covars[gb];

    float wp[8];
    *(float4*)(wp)     = *(const float4*)(&w_s[b][f * 8]);
    *(float4*)(wp + 4) = *(const float4*)(&w_s[b][f * 8 + 4]);
    float4 rh0 = *(const float4*)(in_rho_w + (size_t)idx * 128 + f * 8);
    float4 rh1 = *(const float4*)(in_rho_w + (size_t)idx * 128 + f * 8 + 4);
    float4 ep0 = *(const float4*)(eps_in + (size_t)gb * 128 + f * 8);
    float4 ep1 = *(const float4*)(eps_in + (size_t)gb * 128 + f * 8 + 4);
    float4 cv0 = *(const float4*)(covp + cov * 128 + f * 8);
    float4 cv1 = *(const float4*)(covp + cov * 128 + f * 8 + 4);
    float rh[8] = {rh0.x, rh0.y, rh0.z, rh0.w, rh1.x, rh1.y, rh1.z, rh1.w};
    float ep[8] = {ep0.x, ep0.y, ep0.z, ep0.w, ep1.x, ep1.y, ep1.z, ep1.w};
    float cv[8] = {cv0.x, cv0.y, cv0.z, cv0.w, cv1.x, cv1.y, cv1.z, cv1.w};

    float wi[8];
    float t1 = 0.f, pr = 0.f;
    #pragma unroll
    for (int e = 0; e < 8; ++e) {
      float s = sp(rh[e]);                       // sigma_in
      float w = ftanh(wp[e] + cv[e]) + s * ep[e];
      wi[e] = w;
      t1 += -0.5f * ep[e] * ep[e] - __logf(s);   // post_in part
      pr += logmix(w);                           // prior_in part
    }
    // publish w_in to LDS (own slice; no cross-thread hazard before sync)
    *(float4*)(&w_s[b][f * 8])     = *(float4*)(wp);       // dummy keep padding
    ((float4*)(&w_s[b][f * 8]))[0]     = make_float4(wi[0], wi[1], wi[2], wi[3]);
    *(float4*)(&w_s[b][f * 8 + 4])     = make_float4(wi[4], wi[5], wi[6], wi[7]);

    float red = t1 - pr;
    #pragma unroll
    for (int m = 1; m <= 8; m <<= 1) red += __shfl_xor(red, m, 64);
    if (f == 0) accum = 8.f * wtv * red;
  }
  __syncthreads();

  // -------- phase 2: quarter-wave qw -> (b = qw&7, half = qw>>3), 4 windows -
  const int qw   = tid >> 4;
  const int b2   = qw & (B_PER_BLK - 1);
  const int half = qw >> 3;
  const int gb2  = bbase + b2;

  float wi[8];
  *(float4*)(wi)     = *(const float4*)(&w_s[b2][f * 8]);
  *(float4*)(wi + 4) = *(const float4*)(&w_s[b2][f * 8 + 4]);

  const int rbase = gb2 * 8 + half * 4;
  int4 oi = *(const int4*)(outputs + rbase);
  int4 ni = *(const int4*)(noise + rbase);
  int ov[4]  = {oi.x, oi.y, oi.z, oi.w};
  int nzv[4] = {ni.x, ni.y, ni.z, ni.w};

  #pragma unroll 2
  for (int w = 0; w < 4; ++w) {
    const int r  = rbase + w;
    const int o  = ov[w];
    const int nz = nzv[w];
    const float* wrow = out_w     + (size_t)o  * 128 + f * 8;
    const float* rrow = out_rho_w + (size_t)o  * 128 + f * 8;
    const float* erow = eps_out   + (size_t)r  * 128 + f * 8;
    const float* nrow = out_w     + (size_t)nz * 128 + f * 8;
    float4 mo0 = *(const float4*)wrow,  mo1 = *(const float4*)(wrow + 4);
    float4 ro0 = *(const float4*)rrow,  ro1 = *(const float4*)(rrow + 4);
    float4 eo0 = *(const float4*)erow,  eo1 = *(const float4*)(erow + 4);
    float4 nv0 = *(const float4*)nrow,  nv1 = *(const float4*)(nrow + 4);
    float mo[8] = {mo0.x, mo0.y, mo0.z, mo0.w, mo1.x, mo1.y, mo1.z, mo1.w};
    float ro[8] = {ro0.x, ro0.y, ro0.z, ro0.w, ro1.x, ro1.y, ro1.z, ro1.w};
    float eo[8] = {eo0.x, eo0.y, eo0.z, eo0.w, eo1.x, eo1.y, eo1.z, eo1.w};
    float nv[8] = {nv0.x, nv0.y, nv0.z, nv0.w, nv1.x, nv1.y, nv1.z, nv1.w};

    float t2 = 0.f, d1 = 0.f, d2 = 0.f;
    #pragma unroll
    for (int e = 0; e < 8; ++e) {
      float s  = sp(ro[e]);
      float wo = mo[e] + s * eo[e];
      t2 += -0.5f * eo[e] * eo[e] - __logf(s) - logmix(wo);  // post_out - prior_out
      d1 += wi[e] * wo;
      d2 -= wi[e] * nv[e];
    }
    #pragma unroll
    for (int m = 1; m <= 8; m <<= 1) {
      t2 += __shfl_xor(t2, m, 64);
      d1 += __shfl_xor(d1, m, 64);
      d2 += __shfl_xor(d2, m, 64);
    }
    float term = wtv * t2 + sp(-d1) + sp(-d2);   // -likelihood = sp(-d1)+sp(-d2)
    if (f == 0) accum += term;
  }

  // -------- deterministic block reduction ----------------------------------
  #pragma unroll
  for (int m = 1; m <= 32; m <<= 1) accum += __shfl_xor(accum, m, 64);
  if (lane == 0) red_s[wv] = accum;
  __syncthreads();
  if (tid == 0) {
    double s = (double)red_s[0] + (double)red_s[1] + (double)red_s[2] + (double)red_s[3];
    parts[blockIdx.x] = s;
  }
}

// ---------------------------------------------------------------------------
// Final deterministic reduction: 2048 block partials -> mean
// ---------------------------------------------------------------------------
__global__ void fin_kernel(const double* __restrict__ parts, float* __restrict__ out) {
  __shared__ double s[256];
  const int tid = threadIdx.x;
  double a = 0.0;
  for (int i = tid; i < GRID; i += 256) a += parts[i];
  s[tid] = a;
  __syncthreads();
  for (int st = 128; st > 0; st >>= 1) {
    if (tid < st) s[tid] += s[tid + st];
    __syncthreads();
  }
  if (tid == 0) out[0] = (float)(s[0] / (double)(BATCH * WIN));
}

extern "C" void kernel_launch(void* const* d_in, const int* in_sizes, int n_in,
                              void* d_out, int out_size, void* d_ws, size_t ws_size,
                              hipStream_t stream) {
  const int*   inputs    = (const int*)d_in[0];
  const int*   outputs   = (const int*)d_in[1];
  const int*   covars    = (const int*)d_in[2];
  const int*   noise     = (const int*)d_in[3];
  const float* wt        = (const float*)d_in[4];
  const float* eps_in    = (const float*)d_in[5];
  const float* eps_out   = (const float*)d_in[6];
  const float* in_w      = (const float*)d_in[7];
  const float* out_w     = (const float*)d_in[8];
  const float* in_rho_w  = (const float*)d_in[9];
  const float* out_rho_w = (const float*)d_in[10];
  const float* cov_w     = (const float*)d_in[11];
  const float* lin_w     = (const float*)d_in[12];
  const float* lin_b     = (const float*)d_in[13];

  short*  bpack = (short*)d_ws;                            // 32768 B
  float*  covp  = (float*)((char*)d_ws + 32768);           // 5120 B
  double* parts = (double*)((char*)d_ws + 40960);          // 16384 B

  prep_kernel<<<69, 256, 0, stream>>>(lin_w, lin_b, cov_w, bpack, covp);
  main_kernel<<<GRID, 256, 0, stream>>>(inputs, outputs, covars, noise, wt,
                                        eps_in, eps_out, in_w, out_w,
                                        in_rho_w, out_rho_w, bpack, covp, parts);
  fin_kernel<<<1, 256, 0, stream>>>(parts, (float*)d_out);
}